// Round 6
// baseline (691.177 us; speedup 1.0000x reference)
//
#include <hip/hip_runtime.h>

// y[b,o] = sum_i x[b,i]*W[i,o]*w_mask[b,i,o] + bias[o]*b_mask[b,o]
// B=32, IN_F=1024, OUT_F=4096. f32 tensors, int32 masks.
//
// R2-R5 post-mortem: kernel ~170 us (3 TB/s) invariant to load width,
// occupancy, nt, and register-stationary weights. The one invariant across
// all variants: each block's mask stream was 4 KiB chunks strided 16 KiB
// (o-span 1024 of 4096). Theory T5: strided-chunk streams x512 concurrent
// halve DRAM efficiency. Fix: FULL-ROW blocks — each block owns (b, 64-row
// i-chunk) x the entire O dim, so its mask stream is byte-sequential
// (64 x 16 KiB = 1 MiB, no gaps). 4 int4/thread/row, 4 float4 accumulators.

#define B_DIM 32
#define IN_F 1024
#define OUT_F 4096
#define BO (B_DIM * OUT_F)        // 131072
#define I_CHUNK 64
#define N_CHUNK (IN_F / I_CHUNK)  // 16

typedef int   v4i __attribute__((ext_vector_type(4)));
typedef float v4f __attribute__((ext_vector_type(4)));

// partial[chunk][b][o] : 16 x 32 x 4096 f32 = 8 MiB in d_ws
__global__ __launch_bounds__(256, 2) void masked_gemv_partial(
    const float* __restrict__ x,       // [B, IN_F]
    const float* __restrict__ weight,  // [IN_F, OUT_F]
    const int* __restrict__ w_mask,    // [B, IN_F, OUT_F]
    float* __restrict__ partial)
{
    // bid = b*16 + chunk: weight-row sharers (same chunk, diff b) differ by
    // 16 (16%8==0 -> same XCD round-robin), so each XCD's weight slice is
    // 1 MiB -> L2-resident.
    const int bid   = blockIdx.x;
    const int b     = bid >> 4;
    const int chunk = bid & 15;
    const int i0    = chunk * I_CHUNK;

    __shared__ float xs[I_CHUNK];      // 256 B
    if (threadIdx.x < I_CHUNK) xs[threadIdx.x] = x[b * IN_F + i0 + threadIdx.x];
    __syncthreads();

    const int o4 = threadIdx.x << 2;   // this thread's base o within each 1K pass
    const int* __restrict__ mrow =
        w_mask + ((size_t)b * IN_F + i0) * OUT_F + o4;
    const float* __restrict__ wrow = weight + (size_t)i0 * OUT_F + o4;

    v4f acc0 = {0,0,0,0}, acc1 = {0,0,0,0}, acc2 = {0,0,0,0}, acc3 = {0,0,0,0};

#pragma unroll 2
    for (int i = 0; i < I_CHUNK; ++i) {
        const float xi = xs[i];                       // wave-uniform broadcast
        const size_t r = (size_t)i * OUT_F;
        const v4i m0 = __builtin_nontemporal_load((const v4i*)(mrow + r));
        const v4i m1 = __builtin_nontemporal_load((const v4i*)(mrow + r + 1024));
        const v4i m2 = __builtin_nontemporal_load((const v4i*)(mrow + r + 2048));
        const v4i m3 = __builtin_nontemporal_load((const v4i*)(mrow + r + 3072));
        const v4f w0 = *(const v4f*)(wrow + r);
        const v4f w1 = *(const v4f*)(wrow + r + 1024);
        const v4f w2 = *(const v4f*)(wrow + r + 2048);
        const v4f w3 = *(const v4f*)(wrow + r + 3072);
        // mask is 0/1 -> cndmask instead of cvt+mul
        acc0.x = fmaf(m0.x ? xi : 0.f, w0.x, acc0.x);
        acc0.y = fmaf(m0.y ? xi : 0.f, w0.y, acc0.y);
        acc0.z = fmaf(m0.z ? xi : 0.f, w0.z, acc0.z);
        acc0.w = fmaf(m0.w ? xi : 0.f, w0.w, acc0.w);
        acc1.x = fmaf(m1.x ? xi : 0.f, w1.x, acc1.x);
        acc1.y = fmaf(m1.y ? xi : 0.f, w1.y, acc1.y);
        acc1.z = fmaf(m1.z ? xi : 0.f, w1.z, acc1.z);
        acc1.w = fmaf(m1.w ? xi : 0.f, w1.w, acc1.w);
        acc2.x = fmaf(m2.x ? xi : 0.f, w2.x, acc2.x);
        acc2.y = fmaf(m2.y ? xi : 0.f, w2.y, acc2.y);
        acc2.z = fmaf(m2.z ? xi : 0.f, w2.z, acc2.z);
        acc2.w = fmaf(m2.w ? xi : 0.f, w2.w, acc2.w);
        acc3.x = fmaf(m3.x ? xi : 0.f, w3.x, acc3.x);
        acc3.y = fmaf(m3.y ? xi : 0.f, w3.y, acc3.y);
        acc3.z = fmaf(m3.z ? xi : 0.f, w3.z, acc3.z);
        acc3.w = fmaf(m3.w ? xi : 0.f, w3.w, acc3.w);
    }

    float* prow = partial + ((size_t)chunk * B_DIM + b) * OUT_F + o4;
    __builtin_nontemporal_store(acc0, (v4f*)(prow));
    __builtin_nontemporal_store(acc1, (v4f*)(prow + 1024));
    __builtin_nontemporal_store(acc2, (v4f*)(prow + 2048));
    __builtin_nontemporal_store(acc3, (v4f*)(prow + 3072));
}

__global__ __launch_bounds__(256) void reduce_bias_kernel(
    const float* __restrict__ partial,  // [N_CHUNK][B][OUT_F]
    const float* __restrict__ bias,     // [OUT_F]
    const int* __restrict__ b_mask,     // [B, OUT_F]
    float* __restrict__ out)            // [B, OUT_F]
{
    const int tid = blockIdx.x * 256 + threadIdx.x;  // [0, BO)
    float s = 0.f;
#pragma unroll
    for (int c = 0; c < N_CHUNK; ++c)
        s += partial[(size_t)c * BO + tid];
    const int o = tid & (OUT_F - 1);
    out[tid] = fmaf(bias[o], (float)b_mask[tid], s);
}

extern "C" void kernel_launch(void* const* d_in, const int* in_sizes, int n_in,
                              void* d_out, int out_size, void* d_ws, size_t ws_size,
                              hipStream_t stream) {
    const float* x      = (const float*)d_in[0];
    const float* weight = (const float*)d_in[1];
    const float* bias   = (const float*)d_in[2];
    const int*   w_mask = (const int*)d_in[3];
    const int*   b_mask = (const int*)d_in[4];
    float* out     = (float*)d_out;
    float* partial = (float*)d_ws;  // 8 MiB used

    masked_gemv_partial<<<B_DIM * N_CHUNK, 256, 0, stream>>>(x, weight, w_mask, partial);
    reduce_bias_kernel<<<BO / 256, 256, 0, stream>>>(partial, bias, b_mask, out);
}